// Round 1
// 243.083 us; speedup vs baseline: 1.0146x; 1.0146x over previous
//
#include <hip/hip_runtime.h>

#define N_CELLTYPE 50
#define M_PER_CT   2000
#define N_FEATURE  20000
#define N_CELL     512
#define R_TOTAL    (N_CELLTYPE * M_PER_CT)   // 100000 rows of z
#define TR         256                       // rows per tile (tail tile: 160 rows)
#define TC         32                        // cols per tile (512/32 = 16 exact)
#define NTHREADS   512
#define NRT        ((R_TOTAL + TR - 1) / TR) // 391 row tiles (390*256 + 160)

typedef float vfloat4 __attribute__((ext_vector_type(4)));  // native vec for nt-store

// Gather + scale + transpose via column-major LDS tile.
//   read : x[idx[r]][c0..c0+31] -> 8 lanes/row, full aligned 128B line segments
//   write: out[(c0+c)*100000 + r0 + 4*lane] -> col FIXED per wave, lane = chunk
//          => one wave-store = 1024B contiguous 1KB-aligned burst in one column.
//          This is the whole point vs the previous TR=32 version (128B scattered
//          lines at 400KB stride -> DRAM page thrash, ~2 TB/s effective).
// LDS is tile[c][row] (column-major, NO pad) with XOR swizzle on row bits 2..4:
//   phys_row = row ^ (((c>>1)&7)<<2)
//   - load-phase b32 scatter: banks cover all 32, 2 lanes/bank (free)
//   - store-phase ds_read_b128: c fixed per wave -> swizzle = lane permutation,
//     contiguous conflict-free read; float4 blocks stay intact & 16B aligned.
__global__ __launch_bounds__(NTHREADS) void ct_scale_transpose(
    const float* __restrict__ x, const float* __restrict__ w,
    const int* __restrict__ idx, float* __restrict__ out) {
  __shared__ float tile[TC][TR];   // 32KB; + srow/sw = 34KB -> 4 blocks/CU
  __shared__ int   srow[TR];
  __shared__ float sw[TR];

  const int r0 = blockIdx.x * TR;
  const int c0 = blockIdx.y * TC;
  const int t  = threadIdx.x;

  if (t < TR) {
    const int r = r0 + t;
    if (r < R_TOTAL) {
      srow[t] = idx[r];
      sw[t]   = w[r / M_PER_CT];
    } else {              // tail tile: harmless dummy row, output is guarded
      srow[t] = 0;
      sw[t]   = 0.0f;
    }
  }
  __syncthreads();

  // Load phase: 256 rows x 8 float4 = 2048 float4, 4/thread.
  // Per wave instr: 8 rows x 128B aligned contiguous segments (full lines).
#pragma unroll
  for (int i = 0; i < 4; ++i) {
    const int linear = i * NTHREADS + t;
    const int row = linear >> 3;    // 0..255
    const int q   = linear & 7;     // float4 index within the 32-col slice
    const float4 v = *reinterpret_cast<const float4*>(
        x + (long)srow[row] * N_CELL + c0 + q * 4);
    const float s = sw[row];
    const float e[4] = {v.x * s, v.y * s, v.z * s, v.w * s};
#pragma unroll
    for (int j = 0; j < 4; ++j) {
      const int c    = q * 4 + j;
      const int rswz = row ^ (((c >> 1) & 7) << 2);  // XOR-swizzle bits 2..4
      tile[c][rswz] = e[j];
    }
  }
  __syncthreads();

  // Store phase: 32 cols x 64 float4-chunks = 2048 float4, 4/thread.
  // c = linear>>6 is wave-uniform; lane picks the 4-row chunk ->
  // each wave-store is a single 1KB contiguous aligned burst in one column.
#pragma unroll
  for (int i = 0; i < 4; ++i) {
    const int linear = i * NTHREADS + t;
    const int c    = linear >> 6;               // 0..31, fixed per wave
    const int lane = linear & 63;               // 4-row chunk index
    const int m    = lane ^ ((c >> 1) & 7);     // de-swizzled float4 slot
    const int r    = r0 + lane * 4;
    if (r < R_TOTAL) {                          // tail tile: lanes 0..39 active
      const vfloat4 v = *reinterpret_cast<const vfloat4*>(&tile[c][m * 4]);
      __builtin_nontemporal_store(
          v, reinterpret_cast<vfloat4*>(out + (long)(c0 + c) * R_TOTAL + r));
    }
  }
}

extern "C" void kernel_launch(void* const* d_in, const int* in_sizes, int n_in,
                              void* d_out, int out_size, void* d_ws, size_t ws_size,
                              hipStream_t stream) {
  const float* x   = (const float*)d_in[0];
  const float* w   = (const float*)d_in[1];
  const int*   idx = (const int*)d_in[2];
  float*       out = (float*)d_out;

  dim3 grid(NRT, N_CELL / TC);   // 391 x 16 = 6256 blocks
  ct_scale_transpose<<<grid, NTHREADS, 0, stream>>>(x, w, idx, out);
}